// Round 1
// 143.461 us; speedup vs baseline: 1.0256x; 1.0256x over previous
//
#include <hip/hip_runtime.h>
#include <hip/hip_bf16.h>
#include <stdint.h>
#include <stddef.h>

typedef __bf16 bf16_t;
typedef __bf16 bf16x8 __attribute__((ext_vector_type(8)));
typedef __bf16 bf16x4 __attribute__((ext_vector_type(4)));
typedef float  f32x4  __attribute__((ext_vector_type(4)));

#define NB 8192
#define ND 512
#define NH 2048
#define NHV 512
#define NVO 256
#define RF_TOL 1e-3f
#define NEWTON_MAX 16

typedef const __attribute__((address_space(1))) void gvoid_t;
typedef __attribute__((address_space(3))) void lvoid_t;

__device__ __forceinline__ void gload_lds16(const void* g, void* l) {
  __builtin_amdgcn_global_load_lds((gvoid_t*)g, (lvoid_t*)l, 16, 0, 0);
}

__device__ __forceinline__ float fast_tanhf(float x) {
  x = fminf(fmaxf(x, -15.0f), 15.0f);
  float e = __expf(2.0f * x);
  return (e - 1.0f) * __builtin_amdgcn_rcpf(e + 1.0f);
}

struct GJob {
  const bf16_t* A;    // [8192][K] row-major bf16
  const bf16_t* Bt;   // [N][K] row-major bf16 (pre-transposed B)
  const float*  bias; // [N] or null
  bf16_t* Cbf;        // [8192][N] or null
  float*  Cf;         // [8192][N] or null
  int N, K, nbx, tanh_act;
};

// ---- dual-job GEMM: 128x128 tile, BK=64, dbuf LDS, COUNTED vmcnt pipeline --
// XOR swizzle: logical (row, c) lives at LDS byte row*128 + (c ^ ((row&7)<<4)).
// gload_lds dest is LINEAR; global source is inverse-swizzled (rule #21).
// T4 (counted vmcnt): per K-step issue 8 prefetch loads into buf^1, then wait
// vmcnt(8) — i.e. wait only for the 8 loads issued ONE FULL ITERATION earlier
// (into buf[cur]) — raw s_barrier, NOT __syncthreads (which drains vmcnt(0)
// and exposes full load latency every step; that was the 15% MfmaUtil stall).
__global__ __launch_bounds__(256, 2)
void gemm2_kernel(GJob j0, GJob j1)
{
  __shared__ bf16_t As[2 * 128 * 64];   // 32KB
  __shared__ bf16_t Bs[2 * 128 * 64];   // 32KB
  const bool first = (int)blockIdx.x < j0.nbx;
  const GJob jb = first ? j0 : j1;
  const int bx = (int)blockIdx.x - (first ? 0 : j0.nbx);
  const int K = jb.K, N = jb.N;

  const int t = threadIdx.x, lane = t & 63, w = t >> 6;
  const int wm = w >> 1, wn = w & 1;
  const int la = lane & 15, lg = lane >> 4;
  const size_t m0 = (size_t)blockIdx.y * 128, n0 = (size_t)bx * 128;

  // staging: tile = 128 rows x 128 B = 16KB/operand; thread covers 4 chunks
  size_t soff[4]; int doff[4];
#pragma unroll
  for (int j = 0; j < 4; ++j) {
    const int off = t * 16 + j * 4096;
    const int r = off >> 7, c = off & 127;
    soff[j] = (size_t)r * K + ((c ^ ((r & 7) << 4)) >> 1);  // pre-swizzled source
    doff[j] = off;                                          // linear dest
  }
  const bf16_t* Ab = jb.A + m0 * K;
  const bf16_t* Bb = jb.Bt + n0 * K;

  // fragment LDS byte offsets (swizzled read side)
  int abyte[4][2], bbyte[4][2];
#pragma unroll
  for (int i = 0; i < 4; ++i) {
#pragma unroll
    for (int ks = 0; ks < 2; ++ks) {
      const int ra = wm * 64 + i * 16 + la;
      abyte[i][ks] = ra * 128 + ((ks * 64 + lg * 16) ^ ((ra & 7) << 4));
      const int rb = wn * 64 + i * 16 + la;
      bbyte[i][ks] = rb * 128 + ((ks * 64 + lg * 16) ^ ((rb & 7) << 4));
    }
  }

  f32x4 acc[4][4] = {};
  const int nsteps = K >> 6;

  // prologue: stage tile 0 into buf 0. NO drain here — iter 0's vmcnt(8)
  // covers these 8 loads (8 newer ones will be in flight).
#pragma unroll
  for (int j = 0; j < 4; ++j) {
    gload_lds16(Ab + soff[j], (char*)As + doff[j]);
    gload_lds16(Bb + soff[j], (char*)Bs + doff[j]);
  }

  int cur = 0;
  for (int ts = 0; ts < nsteps; ++ts) {
    const bool pf = (ts + 1 < nsteps);
    if (pf) {                        // issue next-tile loads FIRST (stay in flight)
      const int k0 = (ts + 1) << 6;
      const int dst = (cur ^ 1) * 16384;
#pragma unroll
      for (int j = 0; j < 4; ++j) {
        gload_lds16(Ab + soff[j] + k0, (char*)As + dst + doff[j]);
        gload_lds16(Bb + soff[j] + k0, (char*)Bs + dst + doff[j]);
      }
    }
    // RAW: the 8 loads into buf[cur] (issued last iter / prologue) must be done.
    // Counted wait: 8 newest (into cur^1) may remain outstanding.
    if (pf) asm volatile("s_waitcnt vmcnt(8)" ::: "memory");
    else    asm volatile("s_waitcnt vmcnt(0)" ::: "memory");
    __builtin_amdgcn_s_barrier();    // collective: buf[cur] fully staged
    asm volatile("" ::: "memory");   // keep ds_reads below the barrier

    const char* pa = (const char*)As + cur * 16384;
    const char* pb = (const char*)Bs + cur * 16384;
    bf16x8 afr[4][2], bfr[4][2];
#pragma unroll
    for (int i = 0; i < 4; ++i) {
#pragma unroll
      for (int ks = 0; ks < 2; ++ks) {
        afr[i][ks] = *(const bf16x8*)(pa + abyte[i][ks]);
        bfr[i][ks] = *(const bf16x8*)(pb + bbyte[i][ks]);
      }
    }
#pragma unroll
    for (int ks = 0; ks < 2; ++ks)
#pragma unroll
      for (int i = 0; i < 4; ++i)
#pragma unroll
        for (int j = 0; j < 4; ++j)
          acc[i][j] = __builtin_amdgcn_mfma_f32_16x16x32_bf16(afr[i][ks], bfr[j][ks], acc[i][j], 0, 0, 0);

    if (pf) {                        // WAR: all reads of buf[cur] done before
      asm volatile("" ::: "memory"); //      next iter's prefetch overwrites it
      __builtin_amdgcn_s_barrier();
    }
    cur ^= 1;
  }

  // epilogue (runtime flags; all uniform branches)
#pragma unroll
  for (int i = 0; i < 4; ++i) {
#pragma unroll
    for (int j = 0; j < 4; ++j) {
      const size_t col = n0 + wn * 64 + j * 16 + la;
      const float bv = jb.bias ? jb.bias[col] : 0.0f;
#pragma unroll
      for (int r = 0; r < 4; ++r) {
        const size_t row = m0 + wm * 64 + i * 16 + lg * 4 + r;
        float v = acc[i][j][r] + bv;
        if (jb.tanh_act) v = fast_tanhf(v);
        if (jb.Cbf) jb.Cbf[row * N + col] = (bf16_t)v;
        if (jb.Cf)  jb.Cf [row * N + col] = v;
      }
    }
  }
}

// ------------------ fused prep: 4 transposes + rowcast(x) -------------------
__device__ __forceinline__ void tr_body(const float* __restrict__ src, bf16_t* __restrict__ dst,
                                        int R, int C, int bidx, float (*tile)[33]) {
  const int tilesx = C >> 5;
  const int bi = (bidx / tilesx) << 5, bj = (bidx % tilesx) << 5;
  const int t = threadIdx.x, tx = t & 31, ty = t >> 5;
#pragma unroll
  for (int r = ty; r < 32; r += 8)
    tile[r][tx] = src[(size_t)(bi + r) * C + (bj + tx)];
  __syncthreads();
#pragma unroll
  for (int r = ty; r < 32; r += 8)
    dst[(size_t)(bj + r) * R + (bi + tx)] = (bf16_t)tile[tx][r];
}

__global__ void prep_kernel(const float* __restrict__ x, bf16_t* __restrict__ xbf, float* __restrict__ xsq,
                            const float* __restrict__ W1, bf16_t* __restrict__ w1t,
                            const float* __restrict__ W2, bf16_t* __restrict__ w2t,
                            const float* __restrict__ Wv1, bf16_t* __restrict__ wv1t,
                            const float* __restrict__ Wv2, bf16_t* __restrict__ wv2t)
{
  __shared__ float tile[32][33];
  const int b = blockIdx.x;
  if (b < 1024)      tr_body(W1, w1t, 512, 2048, b, tile);
  else if (b < 2048) tr_body(W2, w2t, 2048, 512, b - 1024, tile);
  else if (b < 2304) tr_body(Wv1, wv1t, 512, 512, b - 2048, tile);
  else if (b < 2432) tr_body(Wv2, wv2t, 512, 256, b - 2304, tile);
  else {
    const int t = threadIdx.x;
    const int row = (b - 2432) * 4 + (t >> 6), l = t & 63;
    const float4* sr = (const float4*)(x + (size_t)row * ND);
    bf16x4* dw = (bf16x4*)(xbf + (size_t)row * ND);
    float s = 0.0f;
#pragma unroll
    for (int c = l; c < ND / 4; c += 64) {
      float4 v = sr[c];
      s = fmaf(v.x, v.x, fmaf(v.y, v.y, fmaf(v.z, v.z, fmaf(v.w, v.w, s))));
      bf16x4 o;
      o[0] = (bf16_t)v.x; o[1] = (bf16_t)v.y; o[2] = (bf16_t)v.z; o[3] = (bf16_t)v.w;
      dw[c] = o;
    }
#pragma unroll
    for (int m = 32; m; m >>= 1) s += __shfl_xor(s, m);
    if (l == 0) xsq[row] = s;
  }
}

// --------- fused post: fsq = sumsq(fbf row), tgt = 0.99*(sumsq(yx)+0.01 xsq)
__global__ void post_kernel(const bf16_t* __restrict__ fbf, const float* __restrict__ yx,
                            const float* __restrict__ xsq,
                            float* __restrict__ fsq, float* __restrict__ tgt)
{
  const int b = blockIdx.x, t = threadIdx.x, l = t & 63;
  if (t < 64) {
    bf16x8 v = *(const bf16x8*)(fbf + (size_t)b * ND + l * 8);
    float s = 0.0f;
#pragma unroll
    for (int q = 0; q < 8; ++q) { float f = (float)v[q]; s = fmaf(f, f, s); }
#pragma unroll
    for (int m = 32; m; m >>= 1) s += __shfl_xor(s, m);
    if (l == 0) fsq[b] = s;
  } else {
    float4 v = ((const float4*)(yx + (size_t)b * NVO))[l];
    float s = fmaf(v.x, v.x, fmaf(v.y, v.y, fmaf(v.z, v.z, v.w * v.w)));
#pragma unroll
    for (int m = 32; m; m >>= 1) s += __shfl_xor(s, m);
    if (l == 0) tgt[b] = 0.99f * (s + 0.01f * xsq[b]);
  }
}

// --------------------------- Newton root-find -------------------------------
// 512 thr (8 waves), 32 samples/block, grid 256. Wv2t frags (128 VGPR) and u0
// (16 VGPR) held in registers across iterations. Per iter:
//  phase A: lanes compute h=tanh(a*u), e=u*(1-h^2) from regs -> swizzled LDS
//  phase B: wave w: cols [w*32,(w+1)*32): accy += h@Wv2, accw += e@Wv2 (B regs)
//  reduce + masked Newton step + early exit.
// Fused epilogue: out[row] = fhat[row] * alpha[row] for this block's 32 rows
// (replaces the separate scale_kernel launch).
__global__ __launch_bounds__(512, 2)
void newton_kernel(const float* __restrict__ u0, const bf16_t* __restrict__ Wv2t,
                   const float* __restrict__ fsq, const float* __restrict__ tgt,
                   const float* __restrict__ fhat, float* __restrict__ out)
{
  __shared__ alignas(16) bf16_t hs[32 * 512];   // 32KB, XOR-swizzled
  __shared__ alignas(16) bf16_t es[32 * 512];
  __shared__ float red[8][32][2];
  __shared__ float alpha_s[32], fsq_s[32], tgt_s[32];
  __shared__ int notdone_s;

  const int t = threadIdx.x, lane = t & 63, w = t >> 6;
  const int la = lane & 15, lg = lane >> 4;
  const int s_base = blockIdx.x * 32;
  const int arow = lane & 31, ahi = lane >> 5;

  // B fragments -> registers (wave w covers VO cols [w*32, w*32+32))
  bf16x8 bfr[2][16];
#pragma unroll
  for (int nt = 0; nt < 2; ++nt) {
    const bf16_t* bp = Wv2t + (size_t)(w * 32 + nt * 16 + la) * NHV + lg * 8;
#pragma unroll
    for (int k = 0; k < 16; ++k)
      bfr[nt][k] = *(const bf16x8*)(bp + k * 32);
  }

  // u0 -> registers (phase-A ownership: row=arow, chunks k8 = w*8+ahi*4+i)
  bf16x8 ureg[4];
#pragma unroll
  for (int i = 0; i < 4; ++i) {
    const float4* p = (const float4*)(u0 + (size_t)(s_base + arow) * NHV + (w * 8 + ahi * 4 + i) * 8);
    float4 v0 = p[0], v1 = p[1];
    bf16x8 hv;
    hv[0] = (bf16_t)v0.x; hv[1] = (bf16_t)v0.y; hv[2] = (bf16_t)v0.z; hv[3] = (bf16_t)v0.w;
    hv[4] = (bf16_t)v1.x; hv[5] = (bf16_t)v1.y; hv[6] = (bf16_t)v1.z; hv[7] = (bf16_t)v1.w;
    ureg[i] = hv;
  }

  if (t < 32) {
    alpha_s[t] = 1.0f;
    fsq_s[t] = fsq[s_base + t];
    tgt_s[t] = tgt[s_base + t];
  }
  __syncthreads();

  for (int it = 0; it < NEWTON_MAX; ++it) {
    // ---- phase A: tanh from registers -> swizzled LDS
    {
      const float c2 = 2.0f * alpha_s[arow];
#pragma unroll
      for (int i = 0; i < 4; ++i) {
        const int k8 = w * 8 + ahi * 4 + i;
        const int byte = (arow << 10) + ((k8 ^ (arow & 7)) << 4);
        bf16x8 uv = ureg[i], hf, ef;
#pragma unroll
        for (int q = 0; q < 8; ++q) {
          float u = (float)uv[q];
          float e = __expf(c2 * u);
          float h = (e - 1.0f) * __builtin_amdgcn_rcpf(e + 1.0f);
          hf[q] = (bf16_t)h;
          ef[q] = (bf16_t)(u * (1.0f - h * h));
        }
        *(bf16x8*)((char*)hs + byte) = hf;
        *(bf16x8*)((char*)es + byte) = ef;
      }
    }
    __syncthreads();

    // ---- phase B: MFMA with register-resident B
    f32x4 accy[2][2] = {};
    f32x4 accw[2][2] = {};
#pragma unroll
    for (int k = 0; k < 16; ++k) {
#pragma unroll
      for (int mt = 0; mt < 2; ++mt) {
        const int row = mt * 16 + la;
        const int byte = (row << 10) + (((k * 4 + lg) ^ (row & 7)) << 4);
        bf16x8 hf = *(const bf16x8*)((const char*)hs + byte);
        bf16x8 ef = *(const bf16x8*)((const char*)es + byte);
#pragma unroll
        for (int nt = 0; nt < 2; ++nt) {
          accy[mt][nt] = __builtin_amdgcn_mfma_f32_16x16x32_bf16(hf, bfr[nt][k], accy[mt][nt], 0, 0, 0);
          accw[mt][nt] = __builtin_amdgcn_mfma_f32_16x16x32_bf16(ef, bfr[nt][k], accw[mt][nt], 0, 0, 0);
        }
      }
    }

    // ---- reduce: SY = sum y^2, SW = sum y*w  (C layout: col=la, row=lg*4+r)
#pragma unroll
    for (int mt = 0; mt < 2; ++mt) {
#pragma unroll
      for (int r = 0; r < 4; ++r) {
        float sy = 0.0f, sw = 0.0f;
#pragma unroll
        for (int nt = 0; nt < 2; ++nt) {
          float yv = accy[mt][nt][r], wv = accw[mt][nt][r];
          sy = fmaf(yv, yv, sy);
          sw = fmaf(yv, wv, sw);
        }
        sy += __shfl_xor(sy, 1); sw += __shfl_xor(sw, 1);
        sy += __shfl_xor(sy, 2); sw += __shfl_xor(sw, 2);
        sy += __shfl_xor(sy, 4); sw += __shfl_xor(sw, 4);
        sy += __shfl_xor(sy, 8); sw += __shfl_xor(sw, 8);
        if (la == 0) {
          red[w][mt * 16 + lg * 4 + r][0] = sy;
          red[w][mt * 16 + lg * 4 + r][1] = sw;
        }
      }
    }
    __syncthreads();
    if (t < 32) {
      float SY = 0.0f, SW = 0.0f;
#pragma unroll
      for (int w8 = 0; w8 < 8; ++w8) {
        SY += red[w8][t][0];
        SW += red[w8][t][1];
      }
      float a = alpha_s[t];
      const float fs = fsq_s[t];
      const float V = SY + 0.01f * a * a * fs;
      const float dV = 2.0f * SW + 0.02f * a * fs;
      const float resid = V - tgt_s[t];
      const bool go = resid > RF_TOL;
      if (go) alpha_s[t] = a - resid / dV;   // ref's masked Newton step
      const int nd = __any(go);
      if (t == 0) notdone_s = nd;
    }
    __syncthreads();
    if (!notdone_s) break;                   // all converged: further iters are no-ops
  }

  // ---- fused scale: out = fhat * alpha for this block's 32 rows
  // (alpha_s coherent: last write was before the loop's trailing __syncthreads)
  {
    const int r = t >> 4;                    // 0..31
    const int c4 = t & 15;                   // 0..15 (float4 lane within row)
    const float a = alpha_s[r];
    const size_t rb = (size_t)(s_base + r) * ND;
    const float4* sp = (const float4*)(fhat + rb);
    float4* dp = (float4*)(out + rb);
#pragma unroll
    for (int jj = 0; jj < 8; ++jj) {
      float4 v = sp[c4 + jj * 16];
      v.x *= a; v.y *= a; v.z *= a; v.w *= a;
      dp[c4 + jj * 16] = v;
    }
  }
}

extern "C" void kernel_launch(void* const* d_in, const int* in_sizes, int n_in,
                              void* d_out, int out_size, void* d_ws, size_t ws_size,
                              hipStream_t stream)
{
  (void)in_sizes; (void)n_in; (void)out_size; (void)ws_size;
  const float* x   = (const float*)d_in[0];
  const float* W1  = (const float*)d_in[1];
  const float* b1  = (const float*)d_in[2];
  const float* W2  = (const float*)d_in[3];
  const float* b2  = (const float*)d_in[4];
  const float* Wv1 = (const float*)d_in[5];
  const float* Wv2 = (const float*)d_in[6];
  float* out = (float*)d_out;

  char* ws = (char*)d_ws;
  size_t off = 0;
  auto alloc = [&](size_t n) { char* p = ws + off; off += (n + 255) & ~(size_t)255; return p; };

  bf16_t* xbf  = (bf16_t*)alloc((size_t)NB * ND * 2);
  bf16_t* w1t  = (bf16_t*)alloc((size_t)NH * ND * 2);
  bf16_t* w2t  = (bf16_t*)alloc((size_t)ND * NH * 2);
  bf16_t* wv1t = (bf16_t*)alloc((size_t)NHV * ND * 2);
  bf16_t* wv2t = (bf16_t*)alloc((size_t)NVO * NHV * 2);
  bf16_t* h1   = (bf16_t*)alloc((size_t)NB * NH * 2);
  float*  fhat = (float*)alloc((size_t)NB * ND * 4);
  bf16_t* fbf  = (bf16_t*)alloc((size_t)NB * ND * 2);
  bf16_t* hx   = (bf16_t*)alloc((size_t)NB * NHV * 2);
  float*  yx   = (float*)alloc((size_t)NB * NVO * 4);
  float*  u0   = (float*)alloc((size_t)NB * NHV * 4);
  float*  xsq  = (float*)alloc((size_t)NB * 4);
  float*  fsq  = (float*)alloc((size_t)NB * 4);
  float*  tgt  = (float*)alloc((size_t)NB * 4);

  // 1. fused prep: W1,W2,Wv1,Wv2 transpose+cast (2432 blocks) + x rowcast (2048)
  prep_kernel<<<4480, 256, 0, stream>>>(x, xbf, xsq, W1, w1t, W2, w2t, Wv1, wv1t, Wv2, wv2t);

  // 2. G1: h1 = tanh(x@W1+b1) [16 bx] + hx = tanh(x@Wv1) [4 bx]  (1280 blocks)
  GJob jh1 { xbf, w1t,  b1,      h1,  nullptr, NH,  ND, NH  / 128, 1 };
  GJob jhx { xbf, wv1t, nullptr, hx,  nullptr, NHV, ND, NHV / 128, 1 };
  gemm2_kernel<<<dim3(NH / 128 + NHV / 128, NB / 128), 256, 0, stream>>>(jh1, jhx);

  // 3. G2: fhat = h1@W2+b2 (f32 + bf16 outputs) [4 bx] + yx = hx@Wv2 [2 bx]
  GJob jf  { h1,  w2t,  b2,      fbf, fhat,    ND,  NH, ND  / 128, 0 };
  GJob jy  { hx,  wv2t, nullptr, nullptr, yx,  NVO, NHV, NVO / 128, 0 };
  gemm2_kernel<<<dim3(ND / 128 + NVO / 128, NB / 128), 256, 0, stream>>>(jf, jy);

  // 4. fused post: fsq (from fbf) + target (from yx, xsq)
  post_kernel<<<NB, 128, 0, stream>>>(fbf, yx, xsq, fsq, tgt);

  // 5. G3: u0 = fbf @ Wv1
  GJob ju  { fbf, wv1t, nullptr, nullptr, u0,  NHV, ND, NHV / 128, 0 };
  gemm2_kernel<<<dim3(NHV / 128, NB / 128), 256, 0, stream>>>(ju, ju);

  // 6. per-sample masked Newton + fused out = fhat * alpha
  newton_kernel<<<NB / 32, 512, 0, stream>>>(u0, wv2t, fsq, tgt, fhat, out);
}

// Round 2
// 139.362 us; speedup vs baseline: 1.0558x; 1.0294x over previous
//
#include <hip/hip_runtime.h>
#include <hip/hip_bf16.h>
#include <stdint.h>
#include <stddef.h>

typedef __bf16 bf16_t;
typedef __bf16 bf16x8 __attribute__((ext_vector_type(8)));
typedef __bf16 bf16x4 __attribute__((ext_vector_type(4)));
typedef float  f32x4  __attribute__((ext_vector_type(4)));

#define NB 8192
#define ND 512
#define NH 2048
#define NHV 512
#define NVO 256
#define RF_TOL 1e-3f
#define NEWTON_MAX 16

typedef const __attribute__((address_space(1))) void gvoid_t;
typedef __attribute__((address_space(3))) void lvoid_t;

__device__ __forceinline__ void gload_lds16(const void* g, void* l) {
  __builtin_amdgcn_global_load_lds((gvoid_t*)g, (lvoid_t*)l, 16, 0, 0);
}

__device__ __forceinline__ float fast_tanhf(float x) {
  x = fminf(fmaxf(x, -15.0f), 15.0f);
  float e = __expf(2.0f * x);
  return (e - 1.0f) * __builtin_amdgcn_rcpf(e + 1.0f);
}

struct GJob {
  const bf16_t* A;    // [8192][K] row-major bf16
  const bf16_t* Bt;   // [N][K] row-major bf16 (pre-transposed B)
  const float*  bias; // [N] or null
  bf16_t* Cbf;        // [8192][N] or null
  float*  Cf;         // [8192][N] or null
  int N, K, nbx, tanh_act;
};

// ---- dual-job GEMM: 128x128 tile, BK=64, SINGLE-buffer LDS (m97 structure) -
// 32KB LDS -> 5 blocks/CU (vs 2 with dbuf). At 128^2 tile, cross-block TLP is
// what hides the global->LDS latency (m114); explicit dbuf halves occupancy
// for no pipeline gain (m99/m100) — that was the 16%-occupancy latency stall.
// XOR swizzle: logical (row, c) lives at LDS byte row*128 + (c ^ ((row&7)<<4)).
// gload_lds dest is LINEAR; global source is inverse-swizzled (rule #21).
__global__ __launch_bounds__(256, 4)
void gemm2_kernel(GJob j0, GJob j1)
{
  __shared__ bf16_t As[128 * 64];   // 16KB
  __shared__ bf16_t Bs[128 * 64];   // 16KB
  const bool first = (int)blockIdx.x < j0.nbx;
  const GJob jb = first ? j0 : j1;
  const int bx = (int)blockIdx.x - (first ? 0 : j0.nbx);
  const int K = jb.K, N = jb.N;

  const int t = threadIdx.x, lane = t & 63, w = t >> 6;
  const int wm = w >> 1, wn = w & 1;
  const int la = lane & 15, lg = lane >> 4;
  const size_t m0 = (size_t)blockIdx.y * 128, n0 = (size_t)bx * 128;

  // staging: tile = 128 rows x 128 B = 16KB/operand; thread covers 4 chunks
  size_t soff[4]; int doff[4];
#pragma unroll
  for (int j = 0; j < 4; ++j) {
    const int off = t * 16 + j * 4096;
    const int r = off >> 7, c = off & 127;
    soff[j] = (size_t)r * K + ((c ^ ((r & 7) << 4)) >> 1);  // pre-swizzled source
    doff[j] = off;                                          // linear dest
  }
  const bf16_t* Ab = jb.A + m0 * K;
  const bf16_t* Bb = jb.Bt + n0 * K;

  // fragment LDS byte offsets (swizzled read side)
  int abyte[4][2], bbyte[4][2];
#pragma unroll
  for (int i = 0; i < 4; ++i) {
#pragma unroll
    for (int ks = 0; ks < 2; ++ks) {
      const int ra = wm * 64 + i * 16 + la;
      abyte[i][ks] = ra * 128 + ((ks * 64 + lg * 16) ^ ((ra & 7) << 4));
      const int rb = wn * 64 + i * 16 + la;
      bbyte[i][ks] = rb * 128 + ((ks * 64 + lg * 16) ^ ((rb & 7) << 4));
    }
  }

  f32x4 acc[4][4] = {};
  const int nsteps = K >> 6;

  for (int ts = 0; ts < nsteps; ++ts) {
    const int k0 = ts << 6;
#pragma unroll
    for (int j = 0; j < 4; ++j) {
      gload_lds16(Ab + soff[j] + k0, (char*)As + doff[j]);
      gload_lds16(Bb + soff[j] + k0, (char*)Bs + doff[j]);
    }
    __syncthreads();                 // drains vmcnt(0): tile staged

    bf16x8 afr[4][2], bfr[4][2];
#pragma unroll
    for (int i = 0; i < 4; ++i) {
#pragma unroll
      for (int ks = 0; ks < 2; ++ks) {
        afr[i][ks] = *(const bf16x8*)((const char*)As + abyte[i][ks]);
        bfr[i][ks] = *(const bf16x8*)((const char*)Bs + bbyte[i][ks]);
      }
    }
#pragma unroll
    for (int ks = 0; ks < 2; ++ks)
#pragma unroll
      for (int i = 0; i < 4; ++i)
#pragma unroll
        for (int j = 0; j < 4; ++j)
          acc[i][j] = __builtin_amdgcn_mfma_f32_16x16x32_bf16(afr[i][ks], bfr[j][ks], acc[i][j], 0, 0, 0);
    __syncthreads();                 // WAR: reads done before next stage
  }

  // epilogue (runtime flags; all uniform branches)
#pragma unroll
  for (int i = 0; i < 4; ++i) {
#pragma unroll
    for (int j = 0; j < 4; ++j) {
      const size_t col = n0 + wn * 64 + j * 16 + la;
      const float bv = jb.bias ? jb.bias[col] : 0.0f;
#pragma unroll
      for (int r = 0; r < 4; ++r) {
        const size_t row = m0 + wm * 64 + i * 16 + lg * 4 + r;
        float v = acc[i][j][r] + bv;
        if (jb.tanh_act) v = fast_tanhf(v);
        if (jb.Cbf) jb.Cbf[row * N + col] = (bf16_t)v;
        if (jb.Cf)  jb.Cf [row * N + col] = v;
      }
    }
  }
}

// ------------------ fused prep: 4 transposes + rowcast(x) -------------------
__device__ __forceinline__ void tr_body(const float* __restrict__ src, bf16_t* __restrict__ dst,
                                        int R, int C, int bidx, float (*tile)[33]) {
  const int tilesx = C >> 5;
  const int bi = (bidx / tilesx) << 5, bj = (bidx % tilesx) << 5;
  const int t = threadIdx.x, tx = t & 31, ty = t >> 5;
#pragma unroll
  for (int r = ty; r < 32; r += 8)
    tile[r][tx] = src[(size_t)(bi + r) * C + (bj + tx)];
  __syncthreads();
#pragma unroll
  for (int r = ty; r < 32; r += 8)
    dst[(size_t)(bj + r) * R + (bi + tx)] = (bf16_t)tile[tx][r];
}

__global__ void prep_kernel(const float* __restrict__ x, bf16_t* __restrict__ xbf, float* __restrict__ xsq,
                            const float* __restrict__ W1, bf16_t* __restrict__ w1t,
                            const float* __restrict__ W2, bf16_t* __restrict__ w2t,
                            const float* __restrict__ Wv1, bf16_t* __restrict__ wv1t,
                            const float* __restrict__ Wv2, bf16_t* __restrict__ wv2t)
{
  __shared__ float tile[32][33];
  const int b = blockIdx.x;
  if (b < 1024)      tr_body(W1, w1t, 512, 2048, b, tile);
  else if (b < 2048) tr_body(W2, w2t, 2048, 512, b - 1024, tile);
  else if (b < 2304) tr_body(Wv1, wv1t, 512, 512, b - 2048, tile);
  else if (b < 2432) tr_body(Wv2, wv2t, 512, 256, b - 2304, tile);
  else {
    const int t = threadIdx.x;
    const int row = (b - 2432) * 4 + (t >> 6), l = t & 63;
    const float4* sr = (const float4*)(x + (size_t)row * ND);
    bf16x4* dw = (bf16x4*)(xbf + (size_t)row * ND);
    float s = 0.0f;
#pragma unroll
    for (int c = l; c < ND / 4; c += 64) {
      float4 v = sr[c];
      s = fmaf(v.x, v.x, fmaf(v.y, v.y, fmaf(v.z, v.z, fmaf(v.w, v.w, s))));
      bf16x4 o;
      o[0] = (bf16_t)v.x; o[1] = (bf16_t)v.y; o[2] = (bf16_t)v.z; o[3] = (bf16_t)v.w;
      dw[c] = o;
    }
#pragma unroll
    for (int m = 32; m; m >>= 1) s += __shfl_xor(s, m);
    if (l == 0) xsq[row] = s;
  }
}

// --------- fused post: fsq = sumsq(fbf row), tgt = 0.99*(sumsq(yx)+0.01 xsq)
__global__ void post_kernel(const bf16_t* __restrict__ fbf, const float* __restrict__ yx,
                            const float* __restrict__ xsq,
                            float* __restrict__ fsq, float* __restrict__ tgt)
{
  const int b = blockIdx.x, t = threadIdx.x, l = t & 63;
  if (t < 64) {
    bf16x8 v = *(const bf16x8*)(fbf + (size_t)b * ND + l * 8);
    float s = 0.0f;
#pragma unroll
    for (int q = 0; q < 8; ++q) { float f = (float)v[q]; s = fmaf(f, f, s); }
#pragma unroll
    for (int m = 32; m; m >>= 1) s += __shfl_xor(s, m);
    if (l == 0) fsq[b] = s;
  } else {
    float4 v = ((const float4*)(yx + (size_t)b * NVO))[l];
    float s = fmaf(v.x, v.x, fmaf(v.y, v.y, fmaf(v.z, v.z, v.w * v.w)));
#pragma unroll
    for (int m = 32; m; m >>= 1) s += __shfl_xor(s, m);
    if (l == 0) tgt[b] = 0.99f * (s + 0.01f * xsq[b]);
  }
}

// --------------------------- Newton root-find -------------------------------
// 512 thr (8 waves), 32 samples/block, grid 256. Wv2t frags (128 VGPR) and u0
// (16 VGPR) held in registers across iterations. Per iter:
//  phase A: lanes compute h=tanh(a*u), e=u*(1-h^2) from regs -> swizzled LDS
//  phase B: wave w: cols [w*32,(w+1)*32): accy += h@Wv2, accw += e@Wv2 (B regs)
//  reduce + masked Newton step + early exit.
// Fused epilogue: out[row] = fhat[row] * alpha[row] for this block's 32 rows.
__global__ __launch_bounds__(512, 2)
void newton_kernel(const float* __restrict__ u0, const bf16_t* __restrict__ Wv2t,
                   const float* __restrict__ fsq, const float* __restrict__ tgt,
                   const float* __restrict__ fhat, float* __restrict__ out)
{
  __shared__ alignas(16) bf16_t hs[32 * 512];   // 32KB, XOR-swizzled
  __shared__ alignas(16) bf16_t es[32 * 512];
  __shared__ float red[8][32][2];
  __shared__ float alpha_s[32], fsq_s[32], tgt_s[32];
  __shared__ int notdone_s;

  const int t = threadIdx.x, lane = t & 63, w = t >> 6;
  const int la = lane & 15, lg = lane >> 4;
  const int s_base = blockIdx.x * 32;
  const int arow = lane & 31, ahi = lane >> 5;

  // B fragments -> registers (wave w covers VO cols [w*32, w*32+32))
  bf16x8 bfr[2][16];
#pragma unroll
  for (int nt = 0; nt < 2; ++nt) {
    const bf16_t* bp = Wv2t + (size_t)(w * 32 + nt * 16 + la) * NHV + lg * 8;
#pragma unroll
    for (int k = 0; k < 16; ++k)
      bfr[nt][k] = *(const bf16x8*)(bp + k * 32);
  }

  // u0 -> registers (phase-A ownership: row=arow, chunks k8 = w*8+ahi*4+i)
  bf16x8 ureg[4];
#pragma unroll
  for (int i = 0; i < 4; ++i) {
    const float4* p = (const float4*)(u0 + (size_t)(s_base + arow) * NHV + (w * 8 + ahi * 4 + i) * 8);
    float4 v0 = p[0], v1 = p[1];
    bf16x8 hv;
    hv[0] = (bf16_t)v0.x; hv[1] = (bf16_t)v0.y; hv[2] = (bf16_t)v0.z; hv[3] = (bf16_t)v0.w;
    hv[4] = (bf16_t)v1.x; hv[5] = (bf16_t)v1.y; hv[6] = (bf16_t)v1.z; hv[7] = (bf16_t)v1.w;
    ureg[i] = hv;
  }

  if (t < 32) {
    alpha_s[t] = 1.0f;
    fsq_s[t] = fsq[s_base + t];
    tgt_s[t] = tgt[s_base + t];
  }
  __syncthreads();

  for (int it = 0; it < NEWTON_MAX; ++it) {
    // ---- phase A: tanh from registers -> swizzled LDS
    {
      const float c2 = 2.0f * alpha_s[arow];
#pragma unroll
      for (int i = 0; i < 4; ++i) {
        const int k8 = w * 8 + ahi * 4 + i;
        const int byte = (arow << 10) + ((k8 ^ (arow & 7)) << 4);
        bf16x8 uv = ureg[i], hf, ef;
#pragma unroll
        for (int q = 0; q < 8; ++q) {
          float u = (float)uv[q];
          float e = __expf(c2 * u);
          float h = (e - 1.0f) * __builtin_amdgcn_rcpf(e + 1.0f);
          hf[q] = (bf16_t)h;
          ef[q] = (bf16_t)(u * (1.0f - h * h));
        }
        *(bf16x8*)((char*)hs + byte) = hf;
        *(bf16x8*)((char*)es + byte) = ef;
      }
    }
    __syncthreads();

    // ---- phase B: MFMA with register-resident B
    f32x4 accy[2][2] = {};
    f32x4 accw[2][2] = {};
#pragma unroll
    for (int k = 0; k < 16; ++k) {
#pragma unroll
      for (int mt = 0; mt < 2; ++mt) {
        const int row = mt * 16 + la;
        const int byte = (row << 10) + (((k * 4 + lg) ^ (row & 7)) << 4);
        bf16x8 hf = *(const bf16x8*)((const char*)hs + byte);
        bf16x8 ef = *(const bf16x8*)((const char*)es + byte);
#pragma unroll
        for (int nt = 0; nt < 2; ++nt) {
          accy[mt][nt] = __builtin_amdgcn_mfma_f32_16x16x32_bf16(hf, bfr[nt][k], accy[mt][nt], 0, 0, 0);
          accw[mt][nt] = __builtin_amdgcn_mfma_f32_16x16x32_bf16(ef, bfr[nt][k], accw[mt][nt], 0, 0, 0);
        }
      }
    }

    // ---- reduce: SY = sum y^2, SW = sum y*w  (C layout: col=la, row=lg*4+r)
#pragma unroll
    for (int mt = 0; mt < 2; ++mt) {
#pragma unroll
      for (int r = 0; r < 4; ++r) {
        float sy = 0.0f, sw = 0.0f;
#pragma unroll
        for (int nt = 0; nt < 2; ++nt) {
          float yv = accy[mt][nt][r], wv = accw[mt][nt][r];
          sy = fmaf(yv, yv, sy);
          sw = fmaf(yv, wv, sw);
        }
        sy += __shfl_xor(sy, 1); sw += __shfl_xor(sw, 1);
        sy += __shfl_xor(sy, 2); sw += __shfl_xor(sw, 2);
        sy += __shfl_xor(sy, 4); sw += __shfl_xor(sw, 4);
        sy += __shfl_xor(sy, 8); sw += __shfl_xor(sw, 8);
        if (la == 0) {
          red[w][mt * 16 + lg * 4 + r][0] = sy;
          red[w][mt * 16 + lg * 4 + r][1] = sw;
        }
      }
    }
    __syncthreads();
    if (t < 32) {
      float SY = 0.0f, SW = 0.0f;
#pragma unroll
      for (int w8 = 0; w8 < 8; ++w8) {
        SY += red[w8][t][0];
        SW += red[w8][t][1];
      }
      float a = alpha_s[t];
      const float fs = fsq_s[t];
      const float V = SY + 0.01f * a * a * fs;
      const float dV = 2.0f * SW + 0.02f * a * fs;
      const float resid = V - tgt_s[t];
      const bool go = resid > RF_TOL;
      if (go) alpha_s[t] = a - resid / dV;   // ref's masked Newton step
      const int nd = __any(go);
      if (t == 0) notdone_s = nd;
    }
    __syncthreads();
    if (!notdone_s) break;                   // all converged: further iters are no-ops
  }

  // ---- fused scale: out = fhat * alpha for this block's 32 rows
  {
    const int r = t >> 4;                    // 0..31
    const int c4 = t & 15;                   // 0..15 (float4 lane within row)
    const float a = alpha_s[r];
    const size_t rb = (size_t)(s_base + r) * ND;
    const float4* sp = (const float4*)(fhat + rb);
    float4* dp = (float4*)(out + rb);
#pragma unroll
    for (int jj = 0; jj < 8; ++jj) {
      float4 v = sp[c4 + jj * 16];
      v.x *= a; v.y *= a; v.z *= a; v.w *= a;
      dp[c4 + jj * 16] = v;
    }
  }
}

extern "C" void kernel_launch(void* const* d_in, const int* in_sizes, int n_in,
                              void* d_out, int out_size, void* d_ws, size_t ws_size,
                              hipStream_t stream)
{
  (void)in_sizes; (void)n_in; (void)out_size; (void)ws_size;
  const float* x   = (const float*)d_in[0];
  const float* W1  = (const float*)d_in[1];
  const float* b1  = (const float*)d_in[2];
  const float* W2  = (const float*)d_in[3];
  const float* b2  = (const float*)d_in[4];
  const float* Wv1 = (const float*)d_in[5];
  const float* Wv2 = (const float*)d_in[6];
  float* out = (float*)d_out;

  char* ws = (char*)d_ws;
  size_t off = 0;
  auto alloc = [&](size_t n) { char* p = ws + off; off += (n + 255) & ~(size_t)255; return p; };

  bf16_t* xbf  = (bf16_t*)alloc((size_t)NB * ND * 2);
  bf16_t* w1t  = (bf16_t*)alloc((size_t)NH * ND * 2);
  bf16_t* w2t  = (bf16_t*)alloc((size_t)ND * NH * 2);
  bf16_t* wv1t = (bf16_t*)alloc((size_t)NHV * ND * 2);
  bf16_t* wv2t = (bf16_t*)alloc((size_t)NVO * NHV * 2);
  bf16_t* h1   = (bf16_t*)alloc((size_t)NB * NH * 2);
  float*  fhat = (float*)alloc((size_t)NB * ND * 4);
  bf16_t* fbf  = (bf16_t*)alloc((size_t)NB * ND * 2);
  bf16_t* hx   = (bf16_t*)alloc((size_t)NB * NHV * 2);
  float*  yx   = (float*)alloc((size_t)NB * NVO * 4);
  float*  u0   = (float*)alloc((size_t)NB * NHV * 4);
  float*  xsq  = (float*)alloc((size_t)NB * 4);
  float*  fsq  = (float*)alloc((size_t)NB * 4);
  float*  tgt  = (float*)alloc((size_t)NB * 4);

  // 1. fused prep: W1,W2,Wv1,Wv2 transpose+cast (2432 blocks) + x rowcast (2048)
  prep_kernel<<<4480, 256, 0, stream>>>(x, xbf, xsq, W1, w1t, W2, w2t, Wv1, wv1t, Wv2, wv2t);

  // 2. G1: h1 = tanh(x@W1+b1) [16 bx] + hx = tanh(x@Wv1) [4 bx]  (1280 blocks)
  GJob jh1 { xbf, w1t,  b1,      h1,  nullptr, NH,  ND, NH  / 128, 1 };
  GJob jhx { xbf, wv1t, nullptr, hx,  nullptr, NHV, ND, NHV / 128, 1 };
  gemm2_kernel<<<dim3(NH / 128 + NHV / 128, NB / 128), 256, 0, stream>>>(jh1, jhx);

  // 3. G2: fhat = h1@W2+b2 (f32 + bf16 outputs) [4 bx] + yx = hx@Wv2 [2 bx]
  GJob jf  { h1,  w2t,  b2,      fbf, fhat,    ND,  NH, ND  / 128, 0 };
  GJob jy  { hx,  wv2t, nullptr, nullptr, yx,  NVO, NHV, NVO / 128, 0 };
  gemm2_kernel<<<dim3(ND / 128 + NVO / 128, NB / 128), 256, 0, stream>>>(jf, jy);

  // 4. fused post: fsq (from fbf) + target (from yx, xsq)
  post_kernel<<<NB, 128, 0, stream>>>(fbf, yx, xsq, fsq, tgt);

  // 5. G3: u0 = fbf @ Wv1
  GJob ju  { fbf, wv1t, nullptr, nullptr, u0,  NHV, ND, NHV / 128, 0 };
  gemm2_kernel<<<dim3(NHV / 128, NB / 128), 256, 0, stream>>>(ju, ju);

  // 6. per-sample masked Newton + fused out = fhat * alpha
  newton_kernel<<<NB / 32, 512, 0, stream>>>(u0, wv2t, fsq, tgt, fhat, out);
}

// Round 3
// 125.149 us; speedup vs baseline: 1.1757x; 1.1136x over previous
//
#include <hip/hip_runtime.h>
#include <hip/hip_bf16.h>
#include <stdint.h>
#include <stddef.h>

typedef __bf16 bf16_t;
typedef __bf16 bf16x8 __attribute__((ext_vector_type(8)));
typedef __bf16 bf16x4 __attribute__((ext_vector_type(4)));
typedef float  f32x4  __attribute__((ext_vector_type(4)));

#define NB 8192
#define ND 512
#define NH 2048
#define NHV 512
#define NVO 256
#define RF_TOL 1e-3f
#define NEWTON_MAX 16

typedef const __attribute__((address_space(1))) void gvoid_t;
typedef __attribute__((address_space(3))) void lvoid_t;

__device__ __forceinline__ void gload_lds16(const void* g, void* l) {
  __builtin_amdgcn_global_load_lds((gvoid_t*)g, (lvoid_t*)l, 16, 0, 0);
}

__device__ __forceinline__ float fast_tanhf(float x) {
  x = fminf(fmaxf(x, -15.0f), 15.0f);
  float e = __expf(2.0f * x);
  return (e - 1.0f) * __builtin_amdgcn_rcpf(e + 1.0f);
}

struct GJob {
  const bf16_t* A;    // [8192][K] row-major bf16
  const bf16_t* Bt;   // [N][K] row-major bf16 (pre-transposed B)
  const float*  bias; // [N] or null
  bf16_t* Cbf;        // [8192][N] or null
  float*  Cf;         // [8192][N] or null
  int N, K, nbx, tanh_act;
};

// ---- dual-job GEMM: BMx128 tile, BK=64, single-buffer LDS (m97 structure) --
// BM=128 for wide-N jobs (G1: 1280 blocks, 5/CU); BM=64 for narrow-N jobs
// (G2: 768 blocks / G3: 512 blocks vs 384/256 at BM=128) — at <2 blocks/CU the
// per-step vmcnt(0) drain has nothing to overlap with (r2: MfmaUtil 14%,
// VALUBusy 8.5%, occupancy 11%); more, smaller blocks restores cross-block TLP.
// XOR swizzle: logical (row, c) lives at LDS byte row*128 + (c ^ ((row&7)<<4)).
// gload_lds dest is LINEAR; global source is inverse-swizzled (rule #21).
template<int BM>
__global__ __launch_bounds__(256, 4)
void gemm_kernel(GJob j0, GJob j1)
{
  constexpr int MI = BM / 32;          // A-frags (16-row) per wave half
  __shared__ bf16_t As[BM * 64];       // BM x 128B  (8KB or 16KB)
  __shared__ bf16_t Bs[128 * 64];      // 16KB
  const bool first = (int)blockIdx.x < j0.nbx;
  const GJob jb = first ? j0 : j1;
  const int bx = (int)blockIdx.x - (first ? 0 : j0.nbx);
  const int K = jb.K, N = jb.N;

  const int t = threadIdx.x, lane = t & 63, w = t >> 6;
  const int wm = w >> 1, wn = w & 1;
  const int la = lane & 15, lg = lane >> 4;
  const size_t m0 = (size_t)blockIdx.y * BM, n0 = (size_t)bx * 128;

  // staging: A tile = BM rows x 128B (MI chunks/thread), B = 128 rows (4)
  size_t soffA[MI], soffB[4]; int doff[4];
#pragma unroll
  for (int j = 0; j < 4; ++j) {
    const int off = t * 16 + j * 4096;
    const int r = off >> 7, c = off & 127;
    const size_t so = (size_t)r * K + ((c ^ ((r & 7) << 4)) >> 1);  // pre-swizzled
    if (j < MI) soffA[j] = so;
    soffB[j] = so;
    doff[j] = off;                                                  // linear dest
  }
  const bf16_t* Ab = jb.A + m0 * K;
  const bf16_t* Bb = jb.Bt + n0 * K;

  // fragment LDS byte offsets (swizzled read side)
  int abyte[MI][2], bbyte[4][2];
#pragma unroll
  for (int ks = 0; ks < 2; ++ks) {
#pragma unroll
    for (int i = 0; i < MI; ++i) {
      const int ra = wm * (BM / 2) + i * 16 + la;
      abyte[i][ks] = ra * 128 + ((ks * 64 + lg * 16) ^ ((ra & 7) << 4));
    }
#pragma unroll
    for (int j = 0; j < 4; ++j) {
      const int rb = wn * 64 + j * 16 + la;
      bbyte[j][ks] = rb * 128 + ((ks * 64 + lg * 16) ^ ((rb & 7) << 4));
    }
  }

  f32x4 acc[MI][4] = {};
  const int nsteps = K >> 6;

  for (int ts = 0; ts < nsteps; ++ts) {
    const int k0 = ts << 6;
#pragma unroll
    for (int j = 0; j < MI; ++j)
      gload_lds16(Ab + soffA[j] + k0, (char*)As + doff[j]);
#pragma unroll
    for (int j = 0; j < 4; ++j)
      gload_lds16(Bb + soffB[j] + k0, (char*)Bs + doff[j]);
    __syncthreads();                 // drains vmcnt(0): tile staged

    bf16x8 afr[MI][2], bfr[4][2];
#pragma unroll
    for (int ks = 0; ks < 2; ++ks) {
#pragma unroll
      for (int i = 0; i < MI; ++i)
        afr[i][ks] = *(const bf16x8*)((const char*)As + abyte[i][ks]);
#pragma unroll
      for (int j = 0; j < 4; ++j)
        bfr[j][ks] = *(const bf16x8*)((const char*)Bs + bbyte[j][ks]);
    }
#pragma unroll
    for (int ks = 0; ks < 2; ++ks)
#pragma unroll
      for (int i = 0; i < MI; ++i)
#pragma unroll
        for (int j = 0; j < 4; ++j)
          acc[i][j] = __builtin_amdgcn_mfma_f32_16x16x32_bf16(afr[i][ks], bfr[j][ks], acc[i][j], 0, 0, 0);
    __syncthreads();                 // WAR: reads done before next stage
  }

  // epilogue (runtime flags; all uniform branches)
#pragma unroll
  for (int i = 0; i < MI; ++i) {
#pragma unroll
    for (int j = 0; j < 4; ++j) {
      const size_t col = n0 + wn * 64 + j * 16 + la;
      const float bv = jb.bias ? jb.bias[col] : 0.0f;
#pragma unroll
      for (int r = 0; r < 4; ++r) {
        const size_t row = m0 + wm * (BM / 2) + i * 16 + lg * 4 + r;
        float v = acc[i][j][r] + bv;
        if (jb.tanh_act) v = fast_tanhf(v);
        if (jb.Cbf) jb.Cbf[row * N + col] = (bf16_t)v;
        if (jb.Cf)  jb.Cf [row * N + col] = v;
      }
    }
  }
}

// ------------------ fused prep: 4 transposes + rowcast(x) -------------------
__device__ __forceinline__ void tr_body(const float* __restrict__ src, bf16_t* __restrict__ dst,
                                        int R, int C, int bidx, float (*tile)[33]) {
  const int tilesx = C >> 5;
  const int bi = (bidx / tilesx) << 5, bj = (bidx % tilesx) << 5;
  const int t = threadIdx.x, tx = t & 31, ty = t >> 5;
#pragma unroll
  for (int r = ty; r < 32; r += 8)
    tile[r][tx] = src[(size_t)(bi + r) * C + (bj + tx)];
  __syncthreads();
#pragma unroll
  for (int r = ty; r < 32; r += 8)
    dst[(size_t)(bj + r) * R + (bi + tx)] = (bf16_t)tile[tx][r];
}

__global__ void prep_kernel(const float* __restrict__ x, bf16_t* __restrict__ xbf, float* __restrict__ xsq,
                            const float* __restrict__ W1, bf16_t* __restrict__ w1t,
                            const float* __restrict__ W2, bf16_t* __restrict__ w2t,
                            const float* __restrict__ Wv1, bf16_t* __restrict__ wv1t,
                            const float* __restrict__ Wv2, bf16_t* __restrict__ wv2t)
{
  __shared__ float tile[32][33];
  const int b = blockIdx.x;
  if (b < 1024)      tr_body(W1, w1t, 512, 2048, b, tile);
  else if (b < 2048) tr_body(W2, w2t, 2048, 512, b - 1024, tile);
  else if (b < 2304) tr_body(Wv1, wv1t, 512, 512, b - 2048, tile);
  else if (b < 2432) tr_body(Wv2, wv2t, 512, 256, b - 2304, tile);
  else {
    const int t = threadIdx.x;
    const int row = (b - 2432) * 4 + (t >> 6), l = t & 63;
    const float4* sr = (const float4*)(x + (size_t)row * ND);
    bf16x4* dw = (bf16x4*)(xbf + (size_t)row * ND);
    float s = 0.0f;
#pragma unroll
    for (int c = l; c < ND / 4; c += 64) {
      float4 v = sr[c];
      s = fmaf(v.x, v.x, fmaf(v.y, v.y, fmaf(v.z, v.z, fmaf(v.w, v.w, s))));
      bf16x4 o;
      o[0] = (bf16_t)v.x; o[1] = (bf16_t)v.y; o[2] = (bf16_t)v.z; o[3] = (bf16_t)v.w;
      dw[c] = o;
    }
#pragma unroll
    for (int m = 32; m; m >>= 1) s += __shfl_xor(s, m);
    if (l == 0) xsq[row] = s;
  }
}

// --------- fused post: fsq = sumsq(fbf row), tgt = 0.99*(sumsq(yx)+0.01 xsq)
__global__ void post_kernel(const bf16_t* __restrict__ fbf, const float* __restrict__ yx,
                            const float* __restrict__ xsq,
                            float* __restrict__ fsq, float* __restrict__ tgt)
{
  const int b = blockIdx.x, t = threadIdx.x, l = t & 63;
  if (t < 64) {
    bf16x8 v = *(const bf16x8*)(fbf + (size_t)b * ND + l * 8);
    float s = 0.0f;
#pragma unroll
    for (int q = 0; q < 8; ++q) { float f = (float)v[q]; s = fmaf(f, f, s); }
#pragma unroll
    for (int m = 32; m; m >>= 1) s += __shfl_xor(s, m);
    if (l == 0) fsq[b] = s;
  } else {
    float4 v = ((const float4*)(yx + (size_t)b * NVO))[l];
    float s = fmaf(v.x, v.x, fmaf(v.y, v.y, fmaf(v.z, v.z, v.w * v.w)));
#pragma unroll
    for (int m = 32; m; m >>= 1) s += __shfl_xor(s, m);
    if (l == 0) tgt[b] = 0.99f * (s + 0.01f * xsq[b]);
  }
}

// --------------------------- Newton root-find -------------------------------
// 512 thr (8 waves), 32 samples/block, grid 256. Wv2t frags (128 VGPR) and u0
// (bf16, 8 VGPR) held in registers across iterations. Per iter:
//  phase A: lanes compute h=tanh(a*u), e=u*(1-h^2) from regs -> swizzled LDS
//  phase B: wave w: cols [w*32,(w+1)*32): accy += h@Wv2, accw += e@Wv2 (B regs)
//  reduce + masked Newton step + early exit.
// Fused epilogue: out[row] = fhat[row] * alpha[row] for this block's 32 rows.
__global__ __launch_bounds__(512, 2)
void newton_kernel(const bf16_t* __restrict__ u0, const bf16_t* __restrict__ Wv2t,
                   const float* __restrict__ fsq, const float* __restrict__ tgt,
                   const float* __restrict__ fhat, float* __restrict__ out)
{
  __shared__ alignas(16) bf16_t hs[32 * 512];   // 32KB, XOR-swizzled
  __shared__ alignas(16) bf16_t es[32 * 512];
  __shared__ float red[8][32][2];
  __shared__ float alpha_s[32], fsq_s[32], tgt_s[32];
  __shared__ int notdone_s;

  const int t = threadIdx.x, lane = t & 63, w = t >> 6;
  const int la = lane & 15, lg = lane >> 4;
  const int s_base = blockIdx.x * 32;
  const int arow = lane & 31, ahi = lane >> 5;

  // B fragments -> registers (wave w covers VO cols [w*32, w*32+32))
  bf16x8 bfr[2][16];
#pragma unroll
  for (int nt = 0; nt < 2; ++nt) {
    const bf16_t* bp = Wv2t + (size_t)(w * 32 + nt * 16 + la) * NHV + lg * 8;
#pragma unroll
    for (int k = 0; k < 16; ++k)
      bfr[nt][k] = *(const bf16x8*)(bp + k * 32);
  }

  // u0 (bf16) -> registers (phase-A ownership: row=arow, chunks k8 = w*8+ahi*4+i)
  bf16x8 ureg[4];
#pragma unroll
  for (int i = 0; i < 4; ++i)
    ureg[i] = *(const bf16x8*)(u0 + (size_t)(s_base + arow) * NHV + (w * 8 + ahi * 4 + i) * 8);

  if (t < 32) {
    alpha_s[t] = 1.0f;
    fsq_s[t] = fsq[s_base + t];
    tgt_s[t] = tgt[s_base + t];
  }
  __syncthreads();

  for (int it = 0; it < NEWTON_MAX; ++it) {
    // ---- phase A: tanh from registers -> swizzled LDS
    {
      const float c2 = 2.0f * alpha_s[arow];
#pragma unroll
      for (int i = 0; i < 4; ++i) {
        const int k8 = w * 8 + ahi * 4 + i;
        const int byte = (arow << 10) + ((k8 ^ (arow & 7)) << 4);
        bf16x8 uv = ureg[i], hf, ef;
#pragma unroll
        for (int q = 0; q < 8; ++q) {
          float u = (float)uv[q];
          float e = __expf(c2 * u);
          float h = (e - 1.0f) * __builtin_amdgcn_rcpf(e + 1.0f);
          hf[q] = (bf16_t)h;
          ef[q] = (bf16_t)(u * (1.0f - h * h));
        }
        *(bf16x8*)((char*)hs + byte) = hf;
        *(bf16x8*)((char*)es + byte) = ef;
      }
    }
    __syncthreads();

    // ---- phase B: MFMA with register-resident B
    f32x4 accy[2][2] = {};
    f32x4 accw[2][2] = {};
#pragma unroll
    for (int k = 0; k < 16; ++k) {
#pragma unroll
      for (int mt = 0; mt < 2; ++mt) {
        const int row = mt * 16 + la;
        const int byte = (row << 10) + (((k * 4 + lg) ^ (row & 7)) << 4);
        bf16x8 hf = *(const bf16x8*)((const char*)hs + byte);
        bf16x8 ef = *(const bf16x8*)((const char*)es + byte);
#pragma unroll
        for (int nt = 0; nt < 2; ++nt) {
          accy[mt][nt] = __builtin_amdgcn_mfma_f32_16x16x32_bf16(hf, bfr[nt][k], accy[mt][nt], 0, 0, 0);
          accw[mt][nt] = __builtin_amdgcn_mfma_f32_16x16x32_bf16(ef, bfr[nt][k], accw[mt][nt], 0, 0, 0);
        }
      }
    }

    // ---- reduce: SY = sum y^2, SW = sum y*w  (C layout: col=la, row=lg*4+r)
#pragma unroll
    for (int mt = 0; mt < 2; ++mt) {
#pragma unroll
      for (int r = 0; r < 4; ++r) {
        float sy = 0.0f, sw = 0.0f;
#pragma unroll
        for (int nt = 0; nt < 2; ++nt) {
          float yv = accy[mt][nt][r], wv = accw[mt][nt][r];
          sy = fmaf(yv, yv, sy);
          sw = fmaf(yv, wv, sw);
        }
        sy += __shfl_xor(sy, 1); sw += __shfl_xor(sw, 1);
        sy += __shfl_xor(sy, 2); sw += __shfl_xor(sw, 2);
        sy += __shfl_xor(sy, 4); sw += __shfl_xor(sw, 4);
        sy += __shfl_xor(sy, 8); sw += __shfl_xor(sw, 8);
        if (la == 0) {
          red[w][mt * 16 + lg * 4 + r][0] = sy;
          red[w][mt * 16 + lg * 4 + r][1] = sw;
        }
      }
    }
    __syncthreads();
    if (t < 32) {
      float SY = 0.0f, SW = 0.0f;
#pragma unroll
      for (int w8 = 0; w8 < 8; ++w8) {
        SY += red[w8][t][0];
        SW += red[w8][t][1];
      }
      float a = alpha_s[t];
      const float fs = fsq_s[t];
      const float V = SY + 0.01f * a * a * fs;
      const float dV = 2.0f * SW + 0.02f * a * fs;
      const float resid = V - tgt_s[t];
      const bool go = resid > RF_TOL;
      if (go) alpha_s[t] = a - resid / dV;   // ref's masked Newton step
      const int nd = __any(go);
      if (t == 0) notdone_s = nd;
    }
    __syncthreads();
    if (!notdone_s) break;                   // all converged: further iters are no-ops
  }

  // ---- fused scale: out = fhat * alpha for this block's 32 rows
  {
    const int r = t >> 4;                    // 0..31
    const int c4 = t & 15;                   // 0..15 (float4 lane within row)
    const float a = alpha_s[r];
    const size_t rb = (size_t)(s_base + r) * ND;
    const float4* sp = (const float4*)(fhat + rb);
    float4* dp = (float4*)(out + rb);
#pragma unroll
    for (int jj = 0; jj < 8; ++jj) {
      float4 v = sp[c4 + jj * 16];
      v.x *= a; v.y *= a; v.z *= a; v.w *= a;
      dp[c4 + jj * 16] = v;
    }
  }
}

extern "C" void kernel_launch(void* const* d_in, const int* in_sizes, int n_in,
                              void* d_out, int out_size, void* d_ws, size_t ws_size,
                              hipStream_t stream)
{
  (void)in_sizes; (void)n_in; (void)out_size; (void)ws_size;
  const float* x   = (const float*)d_in[0];
  const float* W1  = (const float*)d_in[1];
  const float* b1  = (const float*)d_in[2];
  const float* W2  = (const float*)d_in[3];
  const float* b2  = (const float*)d_in[4];
  const float* Wv1 = (const float*)d_in[5];
  const float* Wv2 = (const float*)d_in[6];
  float* out = (float*)d_out;

  char* ws = (char*)d_ws;
  size_t off = 0;
  auto alloc = [&](size_t n) { char* p = ws + off; off += (n + 255) & ~(size_t)255; return p; };

  bf16_t* xbf  = (bf16_t*)alloc((size_t)NB * ND * 2);
  bf16_t* w1t  = (bf16_t*)alloc((size_t)NH * ND * 2);
  bf16_t* w2t  = (bf16_t*)alloc((size_t)ND * NH * 2);
  bf16_t* wv1t = (bf16_t*)alloc((size_t)NHV * ND * 2);
  bf16_t* wv2t = (bf16_t*)alloc((size_t)NVO * NHV * 2);
  bf16_t* h1   = (bf16_t*)alloc((size_t)NB * NH * 2);
  float*  fhat = (float*)alloc((size_t)NB * ND * 4);
  bf16_t* fbf  = (bf16_t*)alloc((size_t)NB * ND * 2);
  bf16_t* hx   = (bf16_t*)alloc((size_t)NB * NHV * 2);
  float*  yx   = (float*)alloc((size_t)NB * NVO * 4);
  bf16_t* u0bf = (bf16_t*)alloc((size_t)NB * NHV * 2);
  float*  xsq  = (float*)alloc((size_t)NB * 4);
  float*  fsq  = (float*)alloc((size_t)NB * 4);
  float*  tgt  = (float*)alloc((size_t)NB * 4);

  // 1. fused prep: W1,W2,Wv1,Wv2 transpose+cast (2432 blocks) + x rowcast (2048)
  prep_kernel<<<4480, 256, 0, stream>>>(x, xbf, xsq, W1, w1t, W2, w2t, Wv1, wv1t, Wv2, wv2t);

  // 2. G1: h1 = tanh(x@W1+b1) [16 bx] + hx = tanh(x@Wv1) [4 bx]
  //    BM=128: 20x64 = 1280 blocks (5/CU)
  GJob jh1 { xbf, w1t,  b1,      h1,  nullptr, NH,  ND, NH  / 128, 1 };
  GJob jhx { xbf, wv1t, nullptr, hx,  nullptr, NHV, ND, NHV / 128, 1 };
  gemm_kernel<128><<<dim3(NH / 128 + NHV / 128, NB / 128), 256, 0, stream>>>(jh1, jhx);

  // 3. G2: fhat = h1@W2+b2 (f32 + bf16 outputs) + yx = hx@Wv2
  //    BM=64: 6x128 = 768 blocks (3/CU) vs 384 at BM=128
  GJob jf  { h1,  w2t,  b2,      fbf, fhat,    ND,  NH, ND  / 128, 0 };
  GJob jy  { hx,  wv2t, nullptr, nullptr, yx,  NVO, NHV, NVO / 128, 0 };
  gemm_kernel<64><<<dim3(ND / 128 + NVO / 128, NB / 64), 256, 0, stream>>>(jf, jy);

  // 4. fused post: fsq (from fbf) + target (from yx, xsq)
  post_kernel<<<NB, 128, 0, stream>>>(fbf, yx, xsq, fsq, tgt);

  // 5. G3: u0 = fbf @ Wv1 (bf16 output — newton casts to bf16 anyway)
  //    BM=64: 4x128 = 512 blocks (2/CU) vs 256 at BM=128
  GJob ju  { fbf, wv1t, nullptr, u0bf, nullptr, NHV, ND, NHV / 128, 0 };
  gemm_kernel<64><<<dim3(NHV / 128, NB / 64), 256, 0, stream>>>(ju, ju);

  // 6. per-sample masked Newton + fused out = fhat * alpha
  newton_kernel<<<NB / 32, 512, 0, stream>>>(u0bf, wv2t, fsq, tgt, fhat, out);
}